// Round 10
// baseline (371.327 us; speedup 1.0000x reference)
//
#include <hip/hip_runtime.h>

namespace {
constexpr int I_N   = 512;
constexpr int R_N   = 16384;
constexpr int NTOT  = 16896;
constexpr int ZW    = NTOT;           // permanently-zero mirror byte (masked neighbors)
constexpr int N_OUT = 10;
constexpr int G     = 248;            // < 256: co-residency slack
constexpr int T     = 1024;
constexpr int NCH   = NTOT / 64;      // 264 chunks of 64 nodes

// workspace layout (bytes)
constexpr size_t OFF_ADJ = 0;                        // NTOT*8 u32 = 540672
constexpr size_t OFF_LUT = 540672;                   // NTOT*8 u32 = 540672 (bit-reversed pack)
constexpr size_t OFF_WPK = OFF_LUT + 540672;         // 1024 u32
constexpr size_t OFF_XPK = OFF_WPK + 4096;           // 2048 u32
constexpr size_t OFF_INJ = OFF_XPK + 8192;           // 8*32*512 u8
constexpr size_t OFF_BAR = OFF_INJ + 131072;         // 64KB: registration + flags
constexpr size_t OFF_ST  = OFF_BAR + 65536;          // ring: 4 slots * 8 groups * 16896B

using u64 = unsigned long long;
using u8  = unsigned char;

// prep_all gid segmentation
constexpr int PA_BIG = NTOT * 8;          // adjenc + lutpk        135168
constexpr int PA_W   = PA_BIG;            // + wpk                 1024
constexpr int PA_X   = PA_W + 1024;       // + xpk2                2048
constexpr int PA_B   = PA_X + 2048;       // + bar zero            9216
constexpr int PA_S   = PA_B + 9216;       // + slot0 state n>=512  32768
constexpr int PA_TOT = PA_S + 32768;      // 180224 = 704*256
}

// ---- cross-XCD (MALL) atomics: one-time registration only ----
__device__ __forceinline__ unsigned afa_sys(unsigned* p) {
  return __hip_atomic_fetch_add(p, 1u, __ATOMIC_RELAXED, __HIP_MEMORY_SCOPE_SYSTEM);
}
__device__ __forceinline__ unsigned lda_sys(const unsigned* p) {
  return __hip_atomic_load(p, __ATOMIC_RELAXED, __HIP_MEMORY_SCOPE_SYSTEM);
}
__device__ __forceinline__ void sta_sys(unsigned* p, unsigned v) {
  __hip_atomic_store(p, v, __ATOMIC_RELAXED, __HIP_MEMORY_SCOPE_SYSTEM);
}
// ---- XCD-local (L2) sc0 ops for flags ----
__device__ __forceinline__ unsigned ld_l2(const unsigned* p) {
  return __hip_atomic_load(p, __ATOMIC_RELAXED, __HIP_MEMORY_SCOPE_AGENT);
}
__device__ __forceinline__ void st_l2(unsigned* p, unsigned v) {
  __hip_atomic_store(p, v, __ATOMIC_RELAXED, __HIP_MEMORY_SCOPE_AGENT);
}
__device__ __forceinline__ uint4 ld16_sc0(const void* p) {
  uint4 v;
  asm volatile("global_load_dwordx4 %0, %1, off sc0\n\ts_waitcnt vmcnt(0)"
               : "=v"(v) : "v"(p) : "memory");
  return v;
}
// 8x8 bit-matrix transpose about the main diagonal (bit(8r+c) <-> bit(8c+r))
__device__ __forceinline__ u64 flipDiag(u64 x) {
  u64 t;
  t = 0x0f0f0f0f00000000ull & (x ^ (x << 28)); x ^= t ^ (t >> 28);
  t = 0x3333000033330000ull & (x ^ (x << 14)); x ^= t ^ (t >> 14);
  t = 0x5500550055005500ull & (x ^ (x << 7));  x ^= t ^ (t >> 7);
  return x;
}

// ---- fused prep ----
__global__ __launch_bounds__(256) void prep_all(
    const int* __restrict__ adj, const int* __restrict__ deg,
    const float* __restrict__ lut, const float* __restrict__ x,
    const float* __restrict__ w_in, const float* __restrict__ init,
    unsigned* __restrict__ adjenc, unsigned* __restrict__ lutpk,
    unsigned* __restrict__ wpk, unsigned* __restrict__ xpk2,
    unsigned* __restrict__ bar, u8* __restrict__ st)
{
  int gid = blockIdx.x * 256 + threadIdx.x;
  if (gid < PA_BIG) {
    int n = gid >> 3, w = gid & 7;
    adjenc[gid] = (w < deg[n]) ? (unsigned)adj[gid] : (unsigned)ZW;
    // lutpk word w of node n, bit i = lut[n][bitrev8(w*32+i)]
    const float* row = lut + (size_t)n * 256;
    unsigned word = 0;
    for (int i = 0; i < 32; ++i) {
      unsigned r = __brev((unsigned)(w * 32 + i)) >> 24;
      word |= (row[r] > 0.5f ? 1u : 0u) << i;
    }
    lutpk[gid] = word;
  } else if (gid < PA_X) {                // wpk[c*512+i], bit b = w_in[c*32+b][i]
    int i2 = gid - PA_W;
    int c = i2 >> 9, i = i2 & 511;
    unsigned w = 0;
    for (int b = 0; b < 32; ++b)
      w |= (w_in[(c * 32 + b) * 512 + i] > 0.5f ? 1u : 0u) << b;
    wpk[i2] = w;
  } else if (gid < PA_B) {                // j = m*32+s*2+c -> xpk2[(s*2+c)*64+m]
    int j = gid - PA_X;
    const float* xp = x + (size_t)j * 32;
    unsigned w = 0;
    for (int b = 0; b < 32; ++b) w |= (xp[b] > 0.5f ? 1u : 0u) << b;
    xpk2[(j & 31) * 64 + (j >> 5)] = w;
  } else if (gid < PA_S) {
    bar[gid - PA_B] = 0u;                 // registration words + flags
  } else {
    int j = gid - PA_S;                   // slot0 state for n>=512, u32-packed
    int g = j >> 12, i = j & 4095;
    int n = I_N + i * 4;
    unsigned v = 0;
    #pragma unroll
    for (int b = 0; b < 4; ++b)
      v |= (init[n + b] > 0.5f ? 0xFFu : 0x00u) << (8 * b);
    *(unsigned*)(st + (size_t)g * NTOT + n) = v;
  }
}

// ---- prep: inj8[g][sc][n] bytes; sc==0 threads also write slot0 state for n<512 ----
__global__ __launch_bounds__(256) void inj_pack(
    const unsigned* __restrict__ wpk, const unsigned* __restrict__ xpk2,
    const float* __restrict__ init, u8* __restrict__ inj8, u8* __restrict__ st)
{
  int gid = blockIdx.x * 256 + threadIdx.x;   // 8*32*512
  int g = gid >> 14, sc = (gid >> 9) & 31, n = gid & 511;
  int c = sc & 1;
  unsigned wb = wpk[c * 512 + n];
  unsigned acc = 0;
  #pragma unroll
  for (int b = 0; b < 8; ++b) {
    unsigned xw = xpk2[sc * 64 + g * 8 + b];
    acc |= (unsigned)(__popc(xw & wb) & 1) << b;
  }
  inj8[gid] = (u8)acc;
  if (sc == 0)
    st[(size_t)g * NTOT + n] = (u8)(((init[n] > 0.5f) ? 0xFFu : 0x00u) ^ acc);
}

// ---- main: per-lane node + double-buffered mirror + phase-overlapped refresh ----
__global__ __launch_bounds__(1024) void reservoir_main(
    const unsigned* __restrict__ adjenc, const unsigned* __restrict__ lutpk,
    const u8* __restrict__ inj8, u8* __restrict__ st, unsigned* __restrict__ bar)
{
  extern __shared__ char dynpad[];           // occupancy pin -> 1 block/CU
  (void)dynpad;
  __shared__ __align__(16) u8 mir[2][16960]; // double-buffered mirror + ZW pad
  __shared__ unsigned lutlds[9216];          // per-lane LUT, 36B stride
  __shared__ int s_grp, s_slot, s_cnt;
  const int tid = threadIdx.x;
  const int lane = tid & 63;

  // --- one-time registration by physical XCD (MALL scope) ---
  if (tid == 0) {
    unsigned xcc;
    asm volatile("s_getreg_b32 %0, hwreg(HW_REG_XCC_ID)" : "=s"(xcc));
    int g = (int)(xcc & 7u);
    s_grp = g;
    s_slot = (int)afa_sys(&bar[32 + g * 16]);
    asm volatile("s_waitcnt vmcnt(0)" ::: "memory");
    unsigned r = afa_sys(&bar[0]);
    if (r == (unsigned)(G - 1)) sta_sys(&bar[16], 1u);
    while (lda_sys(&bar[16]) < 1u) __builtin_amdgcn_s_sleep(2);
    s_cnt = (int)lda_sys(&bar[32 + g * 16]);
  }
  __syncthreads();
  const int g = s_grp;
  const unsigned kcnt = (unsigned)s_cnt;
  const int slot = s_slot;
  const unsigned wpg = kcnt * 16u;                 // waves in my group
  const unsigned wgid = (unsigned)slot * 16u + (unsigned)(tid >> 6);
  const unsigned clo = (wgid * (unsigned)NCH + wpg - 1u) / wpg;
  const unsigned chi = ((wgid + 1u) * (unsigned)NCH + wpg - 1u) / wpg;
  const bool hasC = clo < chi && clo < (unsigned)NCH;

  // preload chunk: adjacency regs + per-lane LUT into LDS
  int n0 = 0; bool isInj0 = false;
  uint4 A0 = {0,0,0,0}, B0 = {0,0,0,0};
  if (hasC) {
    n0 = (int)(clo * 64u) + lane;
    const uint4* ap = reinterpret_cast<const uint4*>(adjenc + ((size_t)n0 << 3));
    A0 = ap[0]; B0 = ap[1];
    #pragma unroll
    for (int w = 0; w < 8; ++w)
      lutlds[tid * 9 + w] = lutpk[((size_t)n0 << 3) + w];
    isInj0 = n0 < I_N;
  }

  // flags: 4B stride, group g compact at [g*64 + slot]
  unsigned* flags = bar + 1024;
  unsigned* fMy = flags + (unsigned)g * 64u + (unsigned)slot;
  // per-thread 16B unit ownership: unit tid (all), unit 1024+tid (tid<32)
  // owner wave of chunk c is floor(c*wpg/NCH); owner block = that >> 4
  const unsigned c0u = (unsigned)tid >> 2;
  const unsigned* f0 = flags + (unsigned)g * 64u + (((c0u * wpg) / (unsigned)NCH) >> 4);
  const unsigned c1u = (1024u + (unsigned)tid) >> 2;
  const unsigned* f1 = flags + (unsigned)g * 64u + (((c1u * wpg) / (unsigned)NCH) >> 4);
  const bool hasU1 = tid < 32;

  u8* gbase = st + (size_t)g * NTOT;               // + (slot&3)*8*NTOT per ring slot

  // init mirror[0] = state 0 (ring slot 0; prep-written, kernel-boundary coherent)
  *reinterpret_cast<uint4*>(&mir[0][tid * 16]) =
      *reinterpret_cast<const uint4*>(gbase + tid * 16);
  if (hasU1)
    *reinterpret_cast<uint4*>(&mir[0][16384 + tid * 16]) =
        *reinterpret_cast<const uint4*>(gbase + 16384 + tid * 16);
  if (tid == 0) { *(u64*)&mir[0][16896] = 0ull; *(u64*)&mir[1][16896] = 0ull; }
  __syncthreads();

  int cur = 0;
  for (int tt = 1; tt <= 64; ++tt) {
    u8* dst = gbase + (size_t)(tt & 3) * (8 * NTOT); // tick-t output = next-state src
    const u8* mb = mir[cur];
    u8* mn = mir[cur ^ 1];
    bool done0 = false, done1 = false;
    const unsigned ttu = (unsigned)tt;

    // --- PHASE A: chunk waves compute; idle waves prefetch posted segments ---
    if (hasC) {
      __builtin_amdgcn_s_setprio(1);
      unsigned b0 = mb[A0.x], b1 = mb[A0.y], b2 = mb[A0.z], b3 = mb[A0.w];
      unsigned b4 = mb[B0.x], b5 = mb[B0.y], b6 = mb[B0.z], b7 = mb[B0.w];
      unsigned lo = b0 | (b1 << 8) | (b2 << 16) | (b3 << 24);
      unsigned hi = b4 | (b5 << 8) | (b6 << 16) | (b7 << 24);
      u64 y = flipDiag(((u64)hi << 32) | lo);
      unsigned out = 0;
      #pragma unroll
      for (int j = 0; j < 8; ++j) {
        unsigned idx = (unsigned)(y >> (8 * j)) & 255u;
        unsigned w = lutlds[tid * 9 + (idx >> 5)];
        out |= ((w >> (idx & 31u)) & 1u) << j;
      }
      __builtin_amdgcn_s_setprio(0);
      if (isInj0 && (tt & 1) == 0 && tt < 64)
        out ^= inj8[(size_t)(g * 32 + (tt >> 1)) * 512 + n0];
      dst[n0] = (u8)out;
      // rare fallback: extra chunks (only if a group got very few blocks)
      for (unsigned c = clo + 1; c < chi && c < (unsigned)NCH; ++c) {
        int n = (int)(c * 64u) + lane;
        const uint4* ap = reinterpret_cast<const uint4*>(adjenc + ((size_t)n << 3));
        uint4 A = ap[0], B = ap[1];
        unsigned d0 = mb[A.x], d1 = mb[A.y], d2 = mb[A.z], d3 = mb[A.w];
        unsigned d4 = mb[B.x], d5 = mb[B.y], d6 = mb[B.z], d7 = mb[B.w];
        unsigned l2 = d0 | (d1 << 8) | (d2 << 16) | (d3 << 24);
        unsigned h2 = d4 | (d5 << 8) | (d6 << 16) | (d7 << 24);
        u64 y2 = flipDiag(((u64)h2 << 32) | l2);
        unsigned o2 = 0;
        #pragma unroll
        for (int j = 0; j < 8; ++j) {
          unsigned idx = (unsigned)(y2 >> (8 * j)) & 255u;
          unsigned w = lutpk[((size_t)n << 3) + (idx >> 5)];
          o2 |= ((w >> (idx & 31u)) & 1u) << j;
        }
        if (n < I_N && (tt & 1) == 0 && tt < 64)
          o2 ^= inj8[(size_t)(g * 32 + (tt >> 1)) * 512 + n];
        dst[n] = (u8)o2;
      }
    } else if (tt < 64) {
      // prefetch my unit(s) of state tt into mir[cur^1] if owner already posted
      #pragma unroll
      for (int rep = 0; rep < 2; ++rep) {
        if (!done0 && ld_l2(f0) >= ttu) {
          *reinterpret_cast<uint4*>(&mn[tid * 16]) = ld16_sc0(dst + tid * 16);
          done0 = true;
        }
        if (hasU1 && !done1 && ld_l2(f1) >= ttu) {
          *reinterpret_cast<uint4*>(&mn[16384 + tid * 16]) =
              ld16_sc0(dst + 16384 + tid * 16);
          done1 = true;
        }
      }
    }
    __syncthreads();                      // drains all compute stores into L2
    if (tid == 0) st_l2(fMy, ttu);        // post: my share of tick tt is visible

    // --- PHASE B: complete mirror for state tt (per-thread residual units) ---
    if (tt < 64) {
      if (!done0) {
        unsigned f; do { f = ld_l2(f0); } while (f < ttu);
        *reinterpret_cast<uint4*>(&mn[tid * 16]) = ld16_sc0(dst + tid * 16);
      }
      if (hasU1 && !done1) {
        unsigned f; do { f = ld_l2(f1); } while (f < ttu);
        *reinterpret_cast<uint4*>(&mn[16384 + tid * 16]) =
            ld16_sc0(dst + 16384 + tid * 16);
      }
      __syncthreads();
    }
    cur ^= 1;
  }
}

// ---- readout: block m = batch (g=m>>3, bit=m&7); final state in ring slot 0 ----
__global__ __launch_bounds__(512) void readout_k(
    const u8* __restrict__ st, const float* __restrict__ Wout,
    const float* __restrict__ bout, float* __restrict__ out)
{
  const int m = blockIdx.x;
  const int gg = m >> 3, b = m & 7;
  const int lane = threadIdx.x & 63;
  const u8* sp = st + (size_t)gg * NTOT + I_N;     // slot 0 plane
  float acc[N_OUT];
  #pragma unroll
  for (int o = 0; o < N_OUT; ++o) acc[o] = 0.f;
  for (int r = threadIdx.x; r < R_N; r += 512) {
    float bf = (float)((sp[r] >> b) & 1u);
    #pragma unroll
    for (int o = 0; o < N_OUT; ++o)
      acc[o] += bf * Wout[(size_t)o * R_N + r];
  }
  #pragma unroll
  for (int o = 0; o < N_OUT; ++o)
    for (int off = 32; off > 0; off >>= 1)
      acc[o] += __shfl_down(acc[o], off);
  __shared__ float red[8][N_OUT];
  if (lane == 0) {
    int w8 = threadIdx.x >> 6;
    #pragma unroll
    for (int o = 0; o < N_OUT; ++o) red[w8][o] = acc[o];
  }
  __syncthreads();
  if (threadIdx.x < N_OUT) {
    float v = bout[threadIdx.x];
    for (int w8 = 0; w8 < 8; ++w8) v += red[w8][threadIdx.x];
    out[m * N_OUT + threadIdx.x] = 1.0f / (1.0f + expf(-v));
  }
}

extern "C" void kernel_launch(void* const* d_in, const int* in_sizes, int n_in,
                              void* d_out, int out_size, void* d_ws, size_t ws_size,
                              hipStream_t stream)
{
  const float* x    = (const float*)d_in[0];
  const float* w_in = (const float*)d_in[1];
  const int*   adj  = (const int*)d_in[2];
  const int*   deg  = (const int*)d_in[4];
  const float* lut  = (const float*)d_in[5];
  const float* init = (const float*)d_in[7];
  const float* Wout = (const float*)d_in[8];
  const float* bout = (const float*)d_in[9];

  char* ws = (char*)d_ws;
  unsigned* adjenc = (unsigned*)(ws + OFF_ADJ);
  unsigned* lutpk  = (unsigned*)(ws + OFF_LUT);
  unsigned* wpk    = (unsigned*)(ws + OFF_WPK);
  unsigned* xpk2   = (unsigned*)(ws + OFF_XPK);
  u8*       inj8   = (u8*)(ws + OFF_INJ);
  unsigned* bar    = (unsigned*)(ws + OFF_BAR);
  u8*       st     = (u8*)(ws + OFF_ST);

  hipLaunchKernelGGL(prep_all, dim3(PA_TOT / 256), dim3(256), 0, stream,
                     adj, deg, lut, x, w_in, init, adjenc, lutpk, wpk, xpk2, bar, st);
  hipLaunchKernelGGL(inj_pack, dim3(512), dim3(256), 0, stream,
                     wpk, xpk2, init, inj8, st);
  hipLaunchKernelGGL(reservoir_main, dim3(G), dim3(T), 60000, stream,
                     adjenc, lutpk, inj8, st, bar);
  hipLaunchKernelGGL(readout_k, dim3(64), dim3(512), 0, stream,
                     st, Wout, bout, (float*)d_out);
}

// Round 12
// 188.232 us; speedup vs baseline: 1.9727x; 1.9727x over previous
//
#include <hip/hip_runtime.h>

namespace {
constexpr int I_N   = 512;
constexpr int R_N   = 16384;
constexpr int NTOT  = 16896;
constexpr int ZW    = NTOT;           // permanently-zero mirror byte (masked neighbors)
constexpr int N_OUT = 10;
constexpr int G     = 248;            // < 256: co-residency slack
constexpr int T     = 1024;
constexpr int NCH   = NTOT / 64;      // 264 chunks of 64 nodes

// workspace layout (bytes)
constexpr size_t OFF_ADJ = 0;                        // NTOT*8 u32 = 540672
constexpr size_t OFF_LUT = 540672;                   // NTOT*8 u32 (bit-reversed pack)
constexpr size_t OFF_WPK = OFF_LUT + 540672;         // 1024 u32
constexpr size_t OFF_XPK = OFF_WPK + 4096;           // 2048 u32
constexpr size_t OFF_INJ = OFF_XPK + 8192;           // 8*32*512 u8
constexpr size_t OFF_BAR = OFF_INJ + 131072;         // 64KB: registration + flags
constexpr size_t OFF_ST  = OFF_BAR + 65536;          // ring4: 4 slots * 8 groups * 16896B

using u64 = unsigned long long;
using u8  = unsigned char;

// prep_all gid segmentation
constexpr int PA_BIG = NTOT * 8;          // adjenc + lutpk        135168
constexpr int PA_W   = PA_BIG;            // + wpk                 1024
constexpr int PA_X   = PA_W + 1024;       // + xpk2                2048
constexpr int PA_B   = PA_X + 2048;       // + bar zero            9216
constexpr int PA_S   = PA_B + 9216;       // + slot0 state n>=512  32768
constexpr int PA_TOT = PA_S + 32768;      // 180224 = 704*256
}

// ---- cross-XCD (MALL) atomics: one-time registration only ----
__device__ __forceinline__ unsigned afa_sys(unsigned* p) {
  return __hip_atomic_fetch_add(p, 1u, __ATOMIC_RELAXED, __HIP_MEMORY_SCOPE_SYSTEM);
}
__device__ __forceinline__ unsigned lda_sys(const unsigned* p) {
  return __hip_atomic_load(p, __ATOMIC_RELAXED, __HIP_MEMORY_SCOPE_SYSTEM);
}
__device__ __forceinline__ void sta_sys(unsigned* p, unsigned v) {
  __hip_atomic_store(p, v, __ATOMIC_RELAXED, __HIP_MEMORY_SCOPE_SYSTEM);
}
// ---- XCD-local (L2) sc0 ops for flags ----
__device__ __forceinline__ unsigned ld_l2(const unsigned* p) {
  return __hip_atomic_load(p, __ATOMIC_RELAXED, __HIP_MEMORY_SCOPE_AGENT);
}
__device__ __forceinline__ void st_l2(unsigned* p, unsigned v) {
  __hip_atomic_store(p, v, __ATOMIC_RELAXED, __HIP_MEMORY_SCOPE_AGENT);
}
// ---- LDS flag-mirror ops (intra-block eager refresh) ----
__device__ __forceinline__ unsigned ld_lds(const unsigned* p) {
  return __hip_atomic_load(p, __ATOMIC_RELAXED, __HIP_MEMORY_SCOPE_WORKGROUP);
}
__device__ __forceinline__ void st_lds(unsigned* p, unsigned v) {
  __hip_atomic_store(p, v, __ATOMIC_RELAXED, __HIP_MEMORY_SCOPE_WORKGROUP);
}
__device__ __forceinline__ uint4 ld16_sc0(const void* p) {
  uint4 v;
  asm volatile("global_load_dwordx4 %0, %1, off sc0\n\ts_waitcnt vmcnt(0)"
               : "=v"(v) : "v"(p) : "memory");
  return v;
}
// 8x8 bit-matrix transpose about the main diagonal (bit(8r+c) <-> bit(8c+r))
__device__ __forceinline__ u64 flipDiag(u64 x) {
  u64 t;
  t = 0x0f0f0f0f00000000ull & (x ^ (x << 28)); x ^= t ^ (t >> 28);
  t = 0x3333000033330000ull & (x ^ (x << 14)); x ^= t ^ (t >> 14);
  t = 0x5500550055005500ull & (x ^ (x << 7));  x ^= t ^ (t >> 7);
  return x;
}

// ---- fused prep ----
__global__ __launch_bounds__(256) void prep_all(
    const int* __restrict__ adj, const int* __restrict__ deg,
    const float* __restrict__ lut, const float* __restrict__ x,
    const float* __restrict__ w_in, const float* __restrict__ init,
    unsigned* __restrict__ adjenc, unsigned* __restrict__ lutpk,
    unsigned* __restrict__ wpk, unsigned* __restrict__ xpk2,
    unsigned* __restrict__ bar, u8* __restrict__ st)
{
  int gid = blockIdx.x * 256 + threadIdx.x;
  if (gid < PA_BIG) {
    int n = gid >> 3, w = gid & 7;
    adjenc[gid] = (w < deg[n]) ? (unsigned)adj[gid] : (unsigned)ZW;
    // lutpk word w of node n, bit i = lut[n][bitrev8(w*32+i)]
    const float* row = lut + (size_t)n * 256;
    unsigned word = 0;
    for (int i = 0; i < 32; ++i) {
      unsigned r = __brev((unsigned)(w * 32 + i)) >> 24;
      word |= (row[r] > 0.5f ? 1u : 0u) << i;
    }
    lutpk[gid] = word;
  } else if (gid < PA_X) {                // wpk[c*512+i], bit b = w_in[c*32+b][i]
    int i2 = gid - PA_W;
    int c = i2 >> 9, i = i2 & 511;
    unsigned w = 0;
    for (int b = 0; b < 32; ++b)
      w |= (w_in[(c * 32 + b) * 512 + i] > 0.5f ? 1u : 0u) << b;
    wpk[i2] = w;
  } else if (gid < PA_B) {                // j = m*32+s*2+c -> xpk2[(s*2+c)*64+m]
    int j = gid - PA_X;
    const float* xp = x + (size_t)j * 32;
    unsigned w = 0;
    for (int b = 0; b < 32; ++b) w |= (xp[b] > 0.5f ? 1u : 0u) << b;
    xpk2[(j & 31) * 64 + (j >> 5)] = w;
  } else if (gid < PA_S) {
    bar[gid - PA_B] = 0u;                 // registration words + flags
  } else {
    int j = gid - PA_S;                   // slot0 state for n>=512, u32-packed
    int g = j >> 12, i = j & 4095;
    int n = I_N + i * 4;
    unsigned v = 0;
    #pragma unroll
    for (int b = 0; b < 4; ++b)
      v |= (init[n + b] > 0.5f ? 0xFFu : 0x00u) << (8 * b);
    *(unsigned*)(st + (size_t)g * NTOT + n) = v;
  }
}

// ---- prep: inj8[g][sc][n] bytes; sc==0 threads also write slot0 state for n<512 ----
__global__ __launch_bounds__(256) void inj_pack(
    const unsigned* __restrict__ wpk, const unsigned* __restrict__ xpk2,
    const float* __restrict__ init, u8* __restrict__ inj8, u8* __restrict__ st)
{
  int gid = blockIdx.x * 256 + threadIdx.x;   // 8*32*512
  int g = gid >> 14, sc = (gid >> 9) & 31, n = gid & 511;
  int c = sc & 1;
  unsigned wb = wpk[c * 512 + n];
  unsigned acc = 0;
  #pragma unroll
  for (int b = 0; b < 8; ++b) {
    unsigned xw = xpk2[sc * 64 + g * 8 + b];
    acc |= (unsigned)(__popc(xw & wb) & 1) << b;
  }
  inj8[gid] = (u8)acc;
  if (sc == 0)
    st[(size_t)g * NTOT + n] = (u8)(((init[n] > 0.5f) ? 0xFFu : 0x00u) ^ acc);
}

// ---- main: per-lane node; wave0 L2-poll + LDS-published flags; eager refresh ----
__global__ __launch_bounds__(1024) void reservoir_main(
    const unsigned* __restrict__ adjenc, const unsigned* __restrict__ lutpk,
    const u8* __restrict__ inj8, u8* __restrict__ st, unsigned* __restrict__ bar)
{
  extern __shared__ char dynpad[];           // occupancy pin -> 1 block/CU
  (void)dynpad;
  __shared__ __align__(16) u8 mir[2][16960]; // double-buffered mirror + ZW pad
  __shared__ unsigned lutlds[9216];          // per-lane LUT, 36B stride
  __shared__ unsigned flagmir[64];           // wave0-published owner flags
  __shared__ int s_grp, s_slot, s_cnt;
  const int tid = threadIdx.x;
  const int lane = tid & 63;

  // --- one-time registration by physical XCD (MALL scope) ---
  if (tid == 0) {
    unsigned xcc;
    asm volatile("s_getreg_b32 %0, hwreg(HW_REG_XCC_ID)" : "=s"(xcc));
    int g = (int)(xcc & 7u);
    s_grp = g;
    s_slot = (int)afa_sys(&bar[32 + g * 16]);
    asm volatile("s_waitcnt vmcnt(0)" ::: "memory");
    unsigned r = afa_sys(&bar[0]);
    if (r == (unsigned)(G - 1)) sta_sys(&bar[16], 1u);
    while (lda_sys(&bar[16]) < 1u) __builtin_amdgcn_s_sleep(2);
    s_cnt = (int)lda_sys(&bar[32 + g * 16]);
  }
  if (tid < 64) flagmir[tid] = 0u;           // init before first use (barrier below)
  __syncthreads();
  const int g = s_grp;
  const unsigned kcnt = (unsigned)s_cnt;
  const int slot = s_slot;
  const unsigned wpg = kcnt * 16u;                 // waves in my group
  const unsigned wgid = (unsigned)slot * 16u + (unsigned)(tid >> 6);
  const unsigned clo = (wgid * (unsigned)NCH + wpg - 1u) / wpg;
  const unsigned chi = ((wgid + 1u) * (unsigned)NCH + wpg - 1u) / wpg;
  const bool hasC = clo < chi && clo < (unsigned)NCH;

  // preload chunk: adjacency regs + per-lane LUT into LDS
  int n0 = 0; bool isInj0 = false;
  uint4 A0 = {0,0,0,0}, B0 = {0,0,0,0};
  if (hasC) {
    n0 = (int)(clo * 64u) + lane;
    const uint4* ap = reinterpret_cast<const uint4*>(adjenc + ((size_t)n0 << 3));
    A0 = ap[0]; B0 = ap[1];
    #pragma unroll
    for (int w = 0; w < 8; ++w)
      lutlds[tid * 9 + w] = lutpk[((size_t)n0 << 3) + w];
    isInj0 = n0 < I_N;
  }

  // flags: 4B stride, group g compact at [g*64 + slot]
  unsigned* flags = bar + 1024;
  unsigned* fMy = flags + (unsigned)g * 64u + (unsigned)slot;
  const unsigned lown = ((unsigned)lane < kcnt) ? (unsigned)lane : 0u;
  const unsigned* fPoll = flags + (unsigned)g * 64u + lown;

  // eager-refresh unit ownership (16B units of the u8 plane; 1056 units; 4/chunk)
  // threads 64..1023 pull: unit (tid-64), and unit 960+(tid-64) if tid-64 < 96
  const int tp = tid - 64;
  unsigned oa = 0, ob = 0; bool hasB = false;
  if (tid >= 64) {
    oa = ((((unsigned)tp >> 2) * wpg) / (unsigned)NCH) >> 4;       // owner slot
    hasB = tp < 96;
    if (hasB) ob = ((((unsigned)(960 + tp) >> 2) * wpg) / (unsigned)NCH) >> 4;
  }

  u8* gbase = st + (size_t)g * NTOT;               // + (tt&3)*8*NTOT per ring slot

  // init mirror[0] = state 0 (ring slot 0; prep-written, kernel-boundary coherent)
  *reinterpret_cast<uint4*>(&mir[0][tid * 16]) =
      *reinterpret_cast<const uint4*>(gbase + tid * 16);
  if (tid < 32)
    *reinterpret_cast<uint4*>(&mir[0][16384 + tid * 16]) =
        *reinterpret_cast<const uint4*>(gbase + 16384 + tid * 16);
  if (tid == 0) { *(u64*)&mir[0][16896] = 0ull; *(u64*)&mir[1][16896] = 0ull; }
  __syncthreads();

  int cur = 0;
  for (int tt = 1; tt <= 64; ++tt) {
    u8* dst = gbase + (size_t)(tt & 3) * (8 * NTOT); // tick-tt output plane
    const u8* mb = mir[cur];
    u8* mn = mir[cur ^ 1];
    const unsigned ttu = (unsigned)tt;

    // --- compute tick tt from mirror (state tt-1) ---
    if (hasC) {
      __builtin_amdgcn_s_setprio(1);
      unsigned b0 = mb[A0.x], b1 = mb[A0.y], b2 = mb[A0.z], b3 = mb[A0.w];
      unsigned b4 = mb[B0.x], b5 = mb[B0.y], b6 = mb[B0.z], b7 = mb[B0.w];
      unsigned lo = b0 | (b1 << 8) | (b2 << 16) | (b3 << 24);
      unsigned hi = b4 | (b5 << 8) | (b6 << 16) | (b7 << 24);
      u64 y = flipDiag(((u64)hi << 32) | lo);
      unsigned out = 0;
      #pragma unroll
      for (int j = 0; j < 8; ++j) {
        unsigned idx = (unsigned)(y >> (8 * j)) & 255u;
        unsigned w = lutlds[tid * 9 + (idx >> 5)];
        out |= ((w >> (idx & 31u)) & 1u) << j;
      }
      __builtin_amdgcn_s_setprio(0);
      if (isInj0 && (tt & 1) == 0 && tt < 64)
        out ^= inj8[(size_t)(g * 32 + (tt >> 1)) * 512 + n0];
      dst[n0] = (u8)out;
      // rare fallback: extra chunks (only if a group got very few blocks)
      for (unsigned c = clo + 1; c < chi && c < (unsigned)NCH; ++c) {
        int n = (int)(c * 64u) + lane;
        const uint4* ap = reinterpret_cast<const uint4*>(adjenc + ((size_t)n << 3));
        uint4 A = ap[0], B = ap[1];
        unsigned d0 = mb[A.x], d1 = mb[A.y], d2 = mb[A.z], d3 = mb[A.w];
        unsigned d4 = mb[B.x], d5 = mb[B.y], d6 = mb[B.z], d7 = mb[B.w];
        unsigned l2 = d0 | (d1 << 8) | (d2 << 16) | (d3 << 24);
        unsigned h2 = d4 | (d5 << 8) | (d6 << 16) | (d7 << 24);
        u64 y2 = flipDiag(((u64)h2 << 32) | l2);
        unsigned o2 = 0;
        #pragma unroll
        for (int j = 0; j < 8; ++j) {
          unsigned idx = (unsigned)(y2 >> (8 * j)) & 255u;
          unsigned w = lutpk[((size_t)n << 3) + (idx >> 5)];
          o2 |= ((w >> (idx & 31u)) & 1u) << j;
        }
        if (n < I_N && (tt & 1) == 0 && tt < 64)
          o2 ^= inj8[(size_t)(g * 32 + (tt >> 1)) * 512 + n];
        dst[n] = (u8)o2;
      }
    }
    __syncthreads();                      // drains all compute stores into L2
    if (tid == 0) st_l2(fMy, ttu);        // post: my share of tick tt is visible

    // --- eager refresh of mirror for state tt (overlapped with straggler wait) ---
    if (tt < 64) {
      if (tid < 64) {
        // wave0: sole L2 poller; publish observed flags to LDS every iteration
        for (;;) {
          unsigned v = ld_l2(fPoll);
          st_lds(&flagmir[lane], v);
          if (__ballot(v < ttu) == 0ull) break;
          __builtin_amdgcn_s_sleep(1);
        }
      } else {
        // waves 1-15: pull own unit(s) as soon as owner appears in flagmir
        while (ld_lds(&flagmir[oa]) < ttu) __builtin_amdgcn_s_sleep(1);
        uint4 va = ld16_sc0(dst + (size_t)tp * 16);
        *reinterpret_cast<uint4*>(&mn[tp * 16]) = va;
        if (hasB) {
          while (ld_lds(&flagmir[ob]) < ttu) __builtin_amdgcn_s_sleep(1);
          uint4 vb = ld16_sc0(dst + (size_t)(960 + tp) * 16);
          *reinterpret_cast<uint4*>(&mn[(960 + tp) * 16]) = vb;
        }
      }
      __syncthreads();                    // mirror complete
      cur ^= 1;
    }
  }
}

// ---- readout: block m = batch (g=m>>3, bit=m&7); final state in ring slot 0 ----
__global__ __launch_bounds__(512) void readout_k(
    const u8* __restrict__ st, const float* __restrict__ Wout,
    const float* __restrict__ bout, float* __restrict__ out)
{
  const int m = blockIdx.x;
  const int gg = m >> 3, b = m & 7;
  const int lane = threadIdx.x & 63;
  const u8* sp = st + (size_t)gg * NTOT + I_N;     // slot 0 plane (tick 64 = slot 0)
  float acc[N_OUT];
  #pragma unroll
  for (int o = 0; o < N_OUT; ++o) acc[o] = 0.f;
  for (int r = threadIdx.x; r < R_N; r += 512) {
    float bf = (float)((sp[r] >> b) & 1u);
    #pragma unroll
    for (int o = 0; o < N_OUT; ++o)
      acc[o] += bf * Wout[(size_t)o * R_N + r];
  }
  #pragma unroll
  for (int o = 0; o < N_OUT; ++o)
    for (int off = 32; off > 0; off >>= 1)
      acc[o] += __shfl_down(acc[o], off);
  __shared__ float red[8][N_OUT];
  if (lane == 0) {
    int w8 = threadIdx.x >> 6;
    #pragma unroll
    for (int o = 0; o < N_OUT; ++o) red[w8][o] = acc[o];
  }
  __syncthreads();
  if (threadIdx.x < N_OUT) {
    float v = bout[threadIdx.x];
    for (int w8 = 0; w8 < 8; ++w8) v += red[w8][threadIdx.x];
    out[m * N_OUT + threadIdx.x] = 1.0f / (1.0f + expf(-v));
  }
}

extern "C" void kernel_launch(void* const* d_in, const int* in_sizes, int n_in,
                              void* d_out, int out_size, void* d_ws, size_t ws_size,
                              hipStream_t stream)
{
  const float* x    = (const float*)d_in[0];
  const float* w_in = (const float*)d_in[1];
  const int*   adj  = (const int*)d_in[2];
  const int*   deg  = (const int*)d_in[4];
  const float* lut  = (const float*)d_in[5];
  const float* init = (const float*)d_in[7];
  const float* Wout = (const float*)d_in[8];
  const float* bout = (const float*)d_in[9];

  char* ws = (char*)d_ws;
  unsigned* adjenc = (unsigned*)(ws + OFF_ADJ);
  unsigned* lutpk  = (unsigned*)(ws + OFF_LUT);
  unsigned* wpk    = (unsigned*)(ws + OFF_WPK);
  unsigned* xpk2   = (unsigned*)(ws + OFF_XPK);
  u8*       inj8   = (u8*)(ws + OFF_INJ);
  unsigned* bar    = (unsigned*)(ws + OFF_BAR);
  u8*       st     = (u8*)(ws + OFF_ST);

  hipLaunchKernelGGL(prep_all, dim3(PA_TOT / 256), dim3(256), 0, stream,
                     adj, deg, lut, x, w_in, init, adjenc, lutpk, wpk, xpk2, bar, st);
  hipLaunchKernelGGL(inj_pack, dim3(512), dim3(256), 0, stream,
                     wpk, xpk2, init, inj8, st);
  hipLaunchKernelGGL(reservoir_main, dim3(G), dim3(T), 60000, stream,
                     adjenc, lutpk, inj8, st, bar);
  hipLaunchKernelGGL(readout_k, dim3(64), dim3(512), 0, stream,
                     st, Wout, bout, (float*)d_out);
}

// Round 13
// 183.210 us; speedup vs baseline: 2.0268x; 1.0274x over previous
//
#include <hip/hip_runtime.h>

namespace {
constexpr int I_N   = 512;
constexpr int R_N   = 16384;
constexpr int NTOT  = 16896;
constexpr int ZW    = NTOT;           // permanently-zero mirror byte (masked neighbors)
constexpr int N_OUT = 10;
constexpr int G     = 248;            // < 256: co-residency slack
constexpr int T     = 1024;
constexpr int NCH   = NTOT / 64;      // 264 chunks of 64 nodes

// workspace layout (bytes)
constexpr size_t OFF_ADJ = 0;                        // NTOT*8 u32 = 540672
constexpr size_t OFF_LUT = 540672;                   // NTOT*8 u32 (bit-reversed pack)
constexpr size_t OFF_WPK = OFF_LUT + 540672;         // 1024 u32
constexpr size_t OFF_XPK = OFF_WPK + 4096;           // 2048 u32
constexpr size_t OFF_INJ = OFF_XPK + 8192;           // 8*32*512 u8
constexpr size_t OFF_BAR = OFF_INJ + 131072;         // 64KB: registration + flags
constexpr size_t OFF_ST  = OFF_BAR + 65536;          // ring: 4 slots * 8 groups * 16896B

using u64 = unsigned long long;
using u8  = unsigned char;

// prep_all gid segmentation
constexpr int PA_BIG = NTOT * 8;          // adjenc + lutpk        135168
constexpr int PA_W   = PA_BIG;            // + wpk                 1024
constexpr int PA_X   = PA_W + 1024;       // + xpk2                2048
constexpr int PA_B   = PA_X + 2048;       // + bar zero            9216
constexpr int PA_S   = PA_B + 9216;       // + slot0 state n>=512  32768
constexpr int PA_TOT = PA_S + 32768;      // 180224 = 704*256
}

// ---- cross-XCD (MALL) atomics: one-time registration only ----
__device__ __forceinline__ unsigned afa_sys(unsigned* p) {
  return __hip_atomic_fetch_add(p, 1u, __ATOMIC_RELAXED, __HIP_MEMORY_SCOPE_SYSTEM);
}
__device__ __forceinline__ unsigned lda_sys(const unsigned* p) {
  return __hip_atomic_load(p, __ATOMIC_RELAXED, __HIP_MEMORY_SCOPE_SYSTEM);
}
__device__ __forceinline__ void sta_sys(unsigned* p, unsigned v) {
  __hip_atomic_store(p, v, __ATOMIC_RELAXED, __HIP_MEMORY_SCOPE_SYSTEM);
}
// ---- XCD-local (L2) sc0 ops for flags ----
__device__ __forceinline__ unsigned ld_l2(const unsigned* p) {
  return __hip_atomic_load(p, __ATOMIC_RELAXED, __HIP_MEMORY_SCOPE_AGENT);
}
__device__ __forceinline__ void st_l2(unsigned* p, unsigned v) {
  __hip_atomic_store(p, v, __ATOMIC_RELAXED, __HIP_MEMORY_SCOPE_AGENT);
}
__device__ __forceinline__ uint4 ld16_sc0(const void* p) {
  uint4 v;
  asm volatile("global_load_dwordx4 %0, %1, off sc0\n\ts_waitcnt vmcnt(0)"
               : "=v"(v) : "v"(p) : "memory");
  return v;
}
// 8x8 bit-matrix transpose about the main diagonal (bit(8r+c) <-> bit(8c+r))
__device__ __forceinline__ u64 flipDiag(u64 x) {
  u64 t;
  t = 0x0f0f0f0f00000000ull & (x ^ (x << 28)); x ^= t ^ (t >> 28);
  t = 0x3333000033330000ull & (x ^ (x << 14)); x ^= t ^ (t >> 14);
  t = 0x5500550055005500ull & (x ^ (x << 7));  x ^= t ^ (t >> 7);
  return x;
}

// ---- fused prep ----
__global__ __launch_bounds__(256) void prep_all(
    const int* __restrict__ adj, const int* __restrict__ deg,
    const float* __restrict__ lut, const float* __restrict__ x,
    const float* __restrict__ w_in, const float* __restrict__ init,
    unsigned* __restrict__ adjenc, unsigned* __restrict__ lutpk,
    unsigned* __restrict__ wpk, unsigned* __restrict__ xpk2,
    unsigned* __restrict__ bar, u8* __restrict__ st)
{
  int gid = blockIdx.x * 256 + threadIdx.x;
  if (gid < PA_BIG) {
    int n = gid >> 3, w = gid & 7;
    adjenc[gid] = (w < deg[n]) ? (unsigned)adj[gid] : (unsigned)ZW;
    // lutpk word w of node n, bit i = lut[n][bitrev8(w*32+i)]
    const float* row = lut + (size_t)n * 256;
    unsigned word = 0;
    for (int i = 0; i < 32; ++i) {
      unsigned r = __brev((unsigned)(w * 32 + i)) >> 24;
      word |= (row[r] > 0.5f ? 1u : 0u) << i;
    }
    lutpk[gid] = word;
  } else if (gid < PA_X) {                // wpk[c*512+i], bit b = w_in[c*32+b][i]
    int i2 = gid - PA_W;
    int c = i2 >> 9, i = i2 & 511;
    unsigned w = 0;
    for (int b = 0; b < 32; ++b)
      w |= (w_in[(c * 32 + b) * 512 + i] > 0.5f ? 1u : 0u) << b;
    wpk[i2] = w;
  } else if (gid < PA_B) {                // j = m*32+s*2+c -> xpk2[(s*2+c)*64+m]
    int j = gid - PA_X;
    const float* xp = x + (size_t)j * 32;
    unsigned w = 0;
    for (int b = 0; b < 32; ++b) w |= (xp[b] > 0.5f ? 1u : 0u) << b;
    xpk2[(j & 31) * 64 + (j >> 5)] = w;
  } else if (gid < PA_S) {
    bar[gid - PA_B] = 0u;                 // registration words + flags
  } else {
    int j = gid - PA_S;                   // slot0 state for n>=512, u32-packed
    int g = j >> 12, i = j & 4095;
    int n = I_N + i * 4;
    unsigned v = 0;
    #pragma unroll
    for (int b = 0; b < 4; ++b)
      v |= (init[n + b] > 0.5f ? 0xFFu : 0x00u) << (8 * b);
    *(unsigned*)(st + (size_t)g * NTOT + n) = v;
  }
}

// ---- prep: inj8[g][sc][n] bytes; sc==0 threads also write slot0 state for n<512 ----
__global__ __launch_bounds__(256) void inj_pack(
    const unsigned* __restrict__ wpk, const unsigned* __restrict__ xpk2,
    const float* __restrict__ init, u8* __restrict__ inj8, u8* __restrict__ st)
{
  int gid = blockIdx.x * 256 + threadIdx.x;   // 8*32*512
  int g = gid >> 14, sc = (gid >> 9) & 31, n = gid & 511;
  int c = sc & 1;
  unsigned wb = wpk[c * 512 + n];
  unsigned acc = 0;
  #pragma unroll
  for (int b = 0; b < 8; ++b) {
    unsigned xw = xpk2[sc * 64 + g * 8 + b];
    acc |= (unsigned)(__popc(xw & wb) & 1) << b;
  }
  inj8[gid] = (u8)acc;
  if (sc == 0)
    st[(size_t)g * NTOT + n] = (u8)(((init[n] > 0.5f) ? 0xFFu : 0x00u) ^ acc);
}

// ---- main: per-lane node, bit-transpose, single-wave poll-all dataflow ----
__global__ __launch_bounds__(1024) void reservoir_main(
    const unsigned* __restrict__ adjenc, const unsigned* __restrict__ lutpk,
    const u8* __restrict__ inj8, u8* __restrict__ st, unsigned* __restrict__ bar)
{
  extern __shared__ char dynpad[];           // occupancy pin -> 1 block/CU
  (void)dynpad;
  __shared__ __align__(16) u8 sstate[16960]; // mirror (16896) + ZW byte
  __shared__ unsigned lutlds[9216];          // per-lane LUT, 36B stride
  __shared__ int s_grp, s_slot, s_cnt;
  const int tid = threadIdx.x;
  const int lane = tid & 63;

  // --- one-time registration by physical XCD (MALL scope) ---
  if (tid == 0) {
    unsigned xcc;
    asm volatile("s_getreg_b32 %0, hwreg(HW_REG_XCC_ID)" : "=s"(xcc));
    int g = (int)(xcc & 7u);
    s_grp = g;
    s_slot = (int)afa_sys(&bar[32 + g * 16]);
    asm volatile("s_waitcnt vmcnt(0)" ::: "memory");
    unsigned r = afa_sys(&bar[0]);
    if (r == (unsigned)(G - 1)) sta_sys(&bar[16], 1u);
    while (lda_sys(&bar[16]) < 1u) __builtin_amdgcn_s_sleep(2);
    s_cnt = (int)lda_sys(&bar[32 + g * 16]);
  }
  __syncthreads();
  const int g = s_grp;
  const unsigned kcnt = (unsigned)s_cnt;
  const int slot = s_slot;
  const unsigned wpg = kcnt * 16u;                 // waves in my group
  const unsigned wgid = (unsigned)slot * 16u + (unsigned)(tid >> 6);
  // chunk range for this wave: {c : floor(c*wpg/NCH) == wgid}
  const unsigned clo = (wgid * (unsigned)NCH + wpg - 1u) / wpg;
  const unsigned chi = ((wgid + 1u) * (unsigned)NCH + wpg - 1u) / wpg;
  const bool hasC = clo < chi && clo < (unsigned)NCH;

  // preload first chunk: adjacency regs + per-lane LUT into LDS
  int n0 = 0; bool isInj0 = false;
  uint4 A0 = {0,0,0,0}, B0 = {0,0,0,0};
  if (hasC) {
    n0 = (int)(clo * 64u) + lane;
    const uint4* ap = reinterpret_cast<const uint4*>(adjenc + ((size_t)n0 << 3));
    A0 = ap[0]; B0 = ap[1];
    #pragma unroll
    for (int w = 0; w < 8; ++w)
      lutlds[tid * 9 + w] = lutpk[((size_t)n0 << 3) + w];
    isInj0 = n0 < I_N;
  }
  if (tid == 0) *(u64*)&sstate[16896] = 0ull;      // ZW byte(s)

  // flags: 4B stride per slot, one compact region per group (2 cache lines)
  unsigned* flags = bar + 1024;                    // flag(g,s) at [g*64 + s]
  unsigned* fMy   = flags + (unsigned)g * 64u + (unsigned)slot;
  const unsigned lown = ((unsigned)lane < kcnt) ? (unsigned)lane : 0u;
  const unsigned* fPoll = flags + (unsigned)g * 64u + lown;

  u8* gbase = st + (size_t)g * NTOT;               // + slot*8*NTOT per ring slot

  for (int tt = 1; tt <= 64; ++tt) {
    const u8* src = gbase + (size_t)((tt - 1) & 3) * (8 * NTOT);
    u8*       dst = gbase + (size_t)(tt & 3) * (8 * NTOT);

    // --- (a) wave 0 polls ALL owner flags >= tt-1 (2 cache lines total) ---
    if (tid < 64) {
      const unsigned need = (unsigned)(tt - 1);
      unsigned v;
      do { v = ld_l2(fPoll); } while (__ballot(v < need) != 0ull);
    }
    __syncthreads();

    // --- (b) coalesced mirror refresh from ring slot ---
    if (tid >= 992) {                               // wave 15 takes the 512B tail
      uint4 v0, v1;
      asm volatile(
        "global_load_dwordx4 %0, %2, off sc0\n\t"
        "global_load_dwordx4 %1, %3, off sc0\n\t"
        "s_waitcnt vmcnt(0)"
        : "=&v"(v0), "=&v"(v1)
        : "v"(src + tid * 16), "v"(src + 16384 + (tid - 992) * 16)
        : "memory");
      *reinterpret_cast<uint4*>(&sstate[tid * 16]) = v0;
      *reinterpret_cast<uint4*>(&sstate[16384 + (tid - 992) * 16]) = v1;
    } else {
      uint4 v0 = ld16_sc0(src + tid * 16);
      *reinterpret_cast<uint4*>(&sstate[tid * 16]) = v0;
    }
    __syncthreads();

    // --- (c) compute: one node per lane ---
    if (hasC) {
      unsigned b0 = sstate[A0.x], b1 = sstate[A0.y];
      unsigned b2 = sstate[A0.z], b3 = sstate[A0.w];
      unsigned b4 = sstate[B0.x], b5 = sstate[B0.y];
      unsigned b6 = sstate[B0.z], b7 = sstate[B0.w];
      unsigned lo = b0 | (b1 << 8) | (b2 << 16) | (b3 << 24);
      unsigned hi = b4 | (b5 << 8) | (b6 << 16) | (b7 << 24);
      u64 y = flipDiag(((u64)hi << 32) | lo);
      unsigned out = 0;
      #pragma unroll
      for (int j = 0; j < 8; ++j) {
        unsigned idx = (unsigned)(y >> (8 * j)) & 255u;
        unsigned w = lutlds[tid * 9 + (idx >> 5)];
        out |= ((w >> (idx & 31u)) & 1u) << j;
      }
      if (isInj0 && (tt & 1) == 0 && tt < 64)
        out ^= inj8[(size_t)(g * 32 + (tt >> 1)) * 512 + n0];
      dst[n0] = (u8)out;
      // rare fallback: extra chunks (only when a group got very few blocks)
      for (unsigned c = clo + 1; c < chi && c < (unsigned)NCH; ++c) {
        int n = (int)(c * 64u) + lane;
        const uint4* ap = reinterpret_cast<const uint4*>(adjenc + ((size_t)n << 3));
        uint4 A = ap[0], B = ap[1];
        unsigned d0 = sstate[A.x], d1 = sstate[A.y], d2 = sstate[A.z], d3 = sstate[A.w];
        unsigned d4 = sstate[B.x], d5 = sstate[B.y], d6 = sstate[B.z], d7 = sstate[B.w];
        unsigned l2 = d0 | (d1 << 8) | (d2 << 16) | (d3 << 24);
        unsigned h2 = d4 | (d5 << 8) | (d6 << 16) | (d7 << 24);
        u64 y2 = flipDiag(((u64)h2 << 32) | l2);
        unsigned o2 = 0;
        #pragma unroll
        for (int j = 0; j < 8; ++j) {
          unsigned idx = (unsigned)(y2 >> (8 * j)) & 255u;
          unsigned w = lutpk[((size_t)n << 3) + (idx >> 5)];
          o2 |= ((w >> (idx & 31u)) & 1u) << j;
        }
        if (n < I_N && (tt & 1) == 0 && tt < 64)
          o2 ^= inj8[(size_t)(g * 32 + (tt >> 1)) * 512 + n];
        dst[n] = (u8)o2;
      }
    }
    __syncthreads();   // drains stores (vmcnt 0) before flag post
    if (tid == 0) st_l2(fMy, (unsigned)tt);        // my share of tick tt is in L2
  }
}

// ---- readout: block m = batch (g=m>>3, bit=m&7); final state in ring slot 0 ----
__global__ __launch_bounds__(512) void readout_k(
    const u8* __restrict__ st, const float* __restrict__ Wout,
    const float* __restrict__ bout, float* __restrict__ out)
{
  const int m = blockIdx.x;
  const int gg = m >> 3, b = m & 7;
  const int lane = threadIdx.x & 63;
  const u8* sp = st + (size_t)gg * NTOT + I_N;     // slot 0 plane
  float acc[N_OUT];
  #pragma unroll
  for (int o = 0; o < N_OUT; ++o) acc[o] = 0.f;
  for (int r = threadIdx.x; r < R_N; r += 512) {
    float bf = (float)((sp[r] >> b) & 1u);
    #pragma unroll
    for (int o = 0; o < N_OUT; ++o)
      acc[o] += bf * Wout[(size_t)o * R_N + r];
  }
  #pragma unroll
  for (int o = 0; o < N_OUT; ++o)
    for (int off = 32; off > 0; off >>= 1)
      acc[o] += __shfl_down(acc[o], off);
  __shared__ float red[8][N_OUT];
  if (lane == 0) {
    int w8 = threadIdx.x >> 6;
    #pragma unroll
    for (int o = 0; o < N_OUT; ++o) red[w8][o] = acc[o];
  }
  __syncthreads();
  if (threadIdx.x < N_OUT) {
    float v = bout[threadIdx.x];
    for (int w8 = 0; w8 < 8; ++w8) v += red[w8][threadIdx.x];
    out[m * N_OUT + threadIdx.x] = 1.0f / (1.0f + expf(-v));
  }
}

extern "C" void kernel_launch(void* const* d_in, const int* in_sizes, int n_in,
                              void* d_out, int out_size, void* d_ws, size_t ws_size,
                              hipStream_t stream)
{
  const float* x    = (const float*)d_in[0];
  const float* w_in = (const float*)d_in[1];
  const int*   adj  = (const int*)d_in[2];
  const int*   deg  = (const int*)d_in[4];
  const float* lut  = (const float*)d_in[5];
  const float* init = (const float*)d_in[7];
  const float* Wout = (const float*)d_in[8];
  const float* bout = (const float*)d_in[9];

  char* ws = (char*)d_ws;
  unsigned* adjenc = (unsigned*)(ws + OFF_ADJ);
  unsigned* lutpk  = (unsigned*)(ws + OFF_LUT);
  unsigned* wpk    = (unsigned*)(ws + OFF_WPK);
  unsigned* xpk2   = (unsigned*)(ws + OFF_XPK);
  u8*       inj8   = (u8*)(ws + OFF_INJ);
  unsigned* bar    = (unsigned*)(ws + OFF_BAR);
  u8*       st     = (u8*)(ws + OFF_ST);

  hipLaunchKernelGGL(prep_all, dim3(PA_TOT / 256), dim3(256), 0, stream,
                     adj, deg, lut, x, w_in, init, adjenc, lutpk, wpk, xpk2, bar, st);
  hipLaunchKernelGGL(inj_pack, dim3(512), dim3(256), 0, stream,
                     wpk, xpk2, init, inj8, st);
  hipLaunchKernelGGL(reservoir_main, dim3(G), dim3(T), 40960, stream,
                     adjenc, lutpk, inj8, st, bar);
  hipLaunchKernelGGL(readout_k, dim3(64), dim3(512), 0, stream,
                     st, Wout, bout, (float*)d_out);
}